// Round 2
// baseline (36.707 us; speedup 1.0000x reference)
//
#include <hip/hip_runtime.h>

// Problem constants (from reference setup_inputs)
static constexpr int N_ROWS = 8192;
static constexpr int D      = 512;
static constexpr int T_LEN  = 2048;
static constexpr float TANH_SCALE = 40.0f;
// Once cumsum > 0.5, tanhf(40*cum) == 1.0f exactly in fp32, so every later
// term of the loss is exactly 0 in the fp32 reference as well -> safe break.
static constexpr float CUT = 0.5f;
static constexpr int NT   = 16;    // columns of l staged in LDS (P(need >16) ~ 4e-5/row)
static constexpr int NBLK = 1024;  // 8 rows per block

__device__ __forceinline__ float row_loss(const float4 p0, const float4 p1,
                                          const float* __restrict__ pfrow,
                                          const float (*lT)[D],
                                          const float* __restrict__ l,
                                          int lane) {
    float cum = 0.0f, loss = 0.0f;
    for (int t = 0; t < NT; ++t) {
        const float* lt = lT[t];
        const float4 a0 = *reinterpret_cast<const float4*>(lt + lane * 4);
        const float4 a1 = *reinterpret_cast<const float4*>(lt + 256 + lane * 4);
        float dot = p0.x * a0.x + p0.y * a0.y + p0.z * a0.z + p0.w * a0.w
                  + p1.x * a1.x + p1.y * a1.y + p1.z * a1.z + p1.w * a1.w;
        #pragma unroll
        for (int off = 32; off > 0; off >>= 1)
            dot += __shfl_xor(dot, off, 64);
        cum += dot * dot;
        loss += pfrow[t] * (0.5f * (1.0f - tanhf(TANH_SCALE * cum)));
        if (cum > CUT) break;                    // wave-uniform
    }
    if (cum <= CUT) {
        // Pathological fallback: direct strided l-column reads. ~Never runs,
        // and when it does, cum saturates within a few more steps.
        for (int t = NT; t < T_LEN; ++t) {
            const int b = lane * 4;
            float dot;
            dot  = p0.x * l[(size_t)(b + 0) * T_LEN + t];
            dot += p0.y * l[(size_t)(b + 1) * T_LEN + t];
            dot += p0.z * l[(size_t)(b + 2) * T_LEN + t];
            dot += p0.w * l[(size_t)(b + 3) * T_LEN + t];
            dot += p1.x * l[(size_t)(256 + b + 0) * T_LEN + t];
            dot += p1.y * l[(size_t)(256 + b + 1) * T_LEN + t];
            dot += p1.z * l[(size_t)(256 + b + 2) * T_LEN + t];
            dot += p1.w * l[(size_t)(256 + b + 3) * T_LEN + t];
            #pragma unroll
            for (int off = 32; off > 0; off >>= 1)
                dot += __shfl_xor(dot, off, 64);
            cum += dot * dot;
            loss += pfrow[t] * (0.5f * (1.0f - tanhf(TANH_SCALE * cum)));
            if (cum > CUT) break;
        }
    }
    return loss;
}

__global__ __launch_bounds__(256, 4) void fused_stopping_loss(
        const float* __restrict__ l,  const float* __restrict__ ps,
        const float* __restrict__ pf, float* __restrict__ partials,
        unsigned int* __restrict__ counter, float* __restrict__ out) {
    __shared__ __align__(16) float lT[NT][D];   // 32 KB
    __shared__ float acc[4];
    __shared__ int lastflag;

    const int tid  = threadIdx.x;
    const int wave = tid >> 6;
    const int lane = tid & 63;
    const int rowA = blockIdx.x * 8 + wave * 2;
    const int rowB = rowA + 1;

    // ps fragments for both rows (issued before staging; coalesced float4)
    const float* psA = ps + (size_t)rowA * D;
    const float* psB = ps + (size_t)rowB * D;
    const float4 pA0 = *reinterpret_cast<const float4*>(psA + lane * 4);
    const float4 pA1 = *reinterpret_cast<const float4*>(psA + 256 + lane * 4);
    const float4 pB0 = *reinterpret_cast<const float4*>(psB + lane * 4);
    const float4 pB1 = *reinterpret_cast<const float4*>(psB + 256 + lane * 4);

    const float* pfA = pf + (size_t)rowA * T_LEN;
    const float* pfB = pf + (size_t)rowB * T_LEN;
    // warm the pf lines (t=0..15 live in one 64B line per row)
    {
        float w0 = pfA[0], w1 = pfB[0];
        asm volatile("" :: "v"(w0), "v"(w1));
    }

    // ---- stage l[:, 0:NT] transposed into LDS (thread i -> rows 2i, 2i+1) ----
    {
        const float* ra = l + (size_t)(2 * tid) * T_LEN;
        const float* rb = ra + T_LEN;
        const float4 a0 = *reinterpret_cast<const float4*>(ra + 0);
        const float4 a1 = *reinterpret_cast<const float4*>(ra + 4);
        const float4 a2 = *reinterpret_cast<const float4*>(ra + 8);
        const float4 a3 = *reinterpret_cast<const float4*>(ra + 12);
        const float4 b0 = *reinterpret_cast<const float4*>(rb + 0);
        const float4 b1 = *reinterpret_cast<const float4*>(rb + 4);
        const float4 b2 = *reinterpret_cast<const float4*>(rb + 8);
        const float4 b3 = *reinterpret_cast<const float4*>(rb + 12);
        const int c = 2 * tid;
        *reinterpret_cast<float2*>(&lT[ 0][c]) = make_float2(a0.x, b0.x);
        *reinterpret_cast<float2*>(&lT[ 1][c]) = make_float2(a0.y, b0.y);
        *reinterpret_cast<float2*>(&lT[ 2][c]) = make_float2(a0.z, b0.z);
        *reinterpret_cast<float2*>(&lT[ 3][c]) = make_float2(a0.w, b0.w);
        *reinterpret_cast<float2*>(&lT[ 4][c]) = make_float2(a1.x, b1.x);
        *reinterpret_cast<float2*>(&lT[ 5][c]) = make_float2(a1.y, b1.y);
        *reinterpret_cast<float2*>(&lT[ 6][c]) = make_float2(a1.z, b1.z);
        *reinterpret_cast<float2*>(&lT[ 7][c]) = make_float2(a1.w, b1.w);
        *reinterpret_cast<float2*>(&lT[ 8][c]) = make_float2(a2.x, b2.x);
        *reinterpret_cast<float2*>(&lT[ 9][c]) = make_float2(a2.y, b2.y);
        *reinterpret_cast<float2*>(&lT[10][c]) = make_float2(a2.z, b2.z);
        *reinterpret_cast<float2*>(&lT[11][c]) = make_float2(a2.w, b2.w);
        *reinterpret_cast<float2*>(&lT[12][c]) = make_float2(a3.x, b3.x);
        *reinterpret_cast<float2*>(&lT[13][c]) = make_float2(a3.y, b3.y);
        *reinterpret_cast<float2*>(&lT[14][c]) = make_float2(a3.z, b3.z);
        *reinterpret_cast<float2*>(&lT[15][c]) = make_float2(a3.w, b3.w);
    }
    __syncthreads();

    const float lossA = row_loss(pA0, pA1, pfA, lT, l, lane);
    const float lossB = row_loss(pB0, pB1, pfB, lT, l, lane);

    if (lane == 0) acc[wave] = lossA + lossB;
    __syncthreads();
    if (tid == 0) {
        partials[blockIdx.x] = (acc[0] + acc[1]) + (acc[2] + acc[3]);
        __threadfence();                          // release partial
        const unsigned old = atomicAdd(counter, 1u);
        lastflag = (old == (unsigned)(NBLK - 1));
    }
    __syncthreads();

    if (lastflag) {                               // exactly one block per call
        __threadfence();                          // acquire all partials
        float s = 0.0f;
        for (int i = tid; i < NBLK; i += 256) s += partials[i];  // fixed order
        #pragma unroll
        for (int off = 32; off > 0; off >>= 1)
            s += __shfl_xor(s, off, 64);
        __syncthreads();
        if (lane == 0) acc[wave] = s;
        __syncthreads();
        if (tid == 0)
            out[0] = -((acc[0] + acc[1]) + (acc[2] + acc[3])) / (float)N_ROWS;
    }
}

extern "C" void kernel_launch(void* const* d_in, const int* in_sizes, int n_in,
                              void* d_out, int out_size, void* d_ws, size_t ws_size,
                              hipStream_t stream) {
    const float* l  = (const float*)d_in[0];   // (512, 2048)
    const float* ps = (const float*)d_in[1];   // (8192, 512)
    const float* pf = (const float*)d_in[2];   // (8192, 2048)
    float* out = (float*)d_out;

    unsigned int* counter = (unsigned int*)d_ws;
    float* partials = (float*)((char*)d_ws + 256);

    hipMemsetAsync(d_ws, 0, 4, stream);        // zero the completion counter
    fused_stopping_loss<<<NBLK, 256, 0, stream>>>(l, ps, pf, partials, counter, out);
}